// Round 15
// baseline (46.925 us; speedup 1.0000x reference)
//
#include <hip/hip_runtime.h>
#include <hip/hip_bf16.h>

// out[i][j] = (x@beta)[i][j] - 0.1*y[i][j]*||beta[:,j]||_1
//             + (4096*rowsum(W2)[j] + bias2[j] + bias_lin[j])
// M=4096, K=2048, N=1024. adv==1 always.
//
// Round 15: NO-LDS, NO-BARRIER register GEMM from L2.
// fp8 operands stored FRAGMENT-MAJOR: frag(mt,ks) = 1KB = lane*16B, where
// lane l holds row=mt*32+(l&31), k = ks*32 + (l>>5)*8 + {0..7}(.x) {16..23}(.y).
// Gemm: 512 blocks x 256 thr; each wave owns a 64x32 output tile and runs 64
// iterations of {3 global_load_dwordx4 (L2-resident) + 4 mfma_32x32x16_fp8}
// with a depth-4 register ring, fully unrolled. No lockstep anywhere.
//   pre_kernel grid 1792: x->fp8 frag-major; beta->fp8 frag-major beta^T +
//   L1 partials [64][1024] via shfl; W2 rowsums.

typedef float    f32x4  __attribute__((ext_vector_type(4)));
typedef float    f32x16 __attribute__((ext_vector_type(16)));
typedef unsigned u32x4  __attribute__((ext_vector_type(4)));
typedef long     lx2    __attribute__((ext_vector_type(2)));

constexpr int M = 4096;
constexpr int N = 1024;
constexpr int K = 2048;
constexpr int NHID = 4096;

__device__ __forceinline__ unsigned pk4f8(float a, float b, float c, float d) {
    unsigned v = __builtin_amdgcn_cvt_pk_fp8_f32(a, b, 0, false);
    v = __builtin_amdgcn_cvt_pk_fp8_f32(c, d, v, true);
    return v;
}

// =================== pre ====================================================
// grid 1792: [0,1024) x 64x128 tiles -> xa fp8 frag-major;
//            [1024,1536) beta 64x64 tiles -> bt fp8 frag-major + L1 partials;
//            [1536,1792) W2 row sums.
__global__ void __launch_bounds__(256) pre_kernel(
    const float* __restrict__ x, const float* __restrict__ beta,
    const float* __restrict__ W2,
    char* __restrict__ xa, char* __restrict__ bt,
    float* __restrict__ partials,   // [64][1024]
    float* __restrict__ wsum) {     // [1024]
    __shared__ float tls[64 * 132];
    const int bx = blockIdx.x, tid = threadIdx.x;
    if (bx < 1024) {
        // ---- x tile: rows rt*64..+63, k kt*128..+127 ----
        const int rt = bx >> 4, kt = bx & 15;
        {   // phase 1: 64x128 f32 tile -> LDS
            const int r = tid >> 2, c0 = (tid & 3) * 32;
            const float* src = x + (size_t)(rt * 64 + r) * K + kt * 128 + c0;
            #pragma unroll
            for (int i = 0; i < 8; ++i)
                *(f32x4*)&tls[r * 132 + c0 + i * 4] = *(const f32x4*)(src + i * 4);
        }
        __syncthreads();
        {   // phase 2: frag-major fp8 pack. f = tid>>5 -> (mtL=f>>2, ksL=f&3);
            // lp = tid&31: row r = mtL*32+lp; writes lanes lp (h=0), lp+32 (h=1)
            const int f = tid >> 5, lp = tid & 31;
            const int mtL = f >> 2, ksL = f & 3;
            const float* fr = &tls[(mtL * 32 + lp) * 132 + ksL * 32];
            const size_t fbase =
                ((size_t)(rt * 2 + mtL) * 64 + (kt * 4 + ksL)) * 1024;
            u32x4 o0 = { pk4f8(fr[0],  fr[1],  fr[2],  fr[3]),
                         pk4f8(fr[4],  fr[5],  fr[6],  fr[7]),
                         pk4f8(fr[16], fr[17], fr[18], fr[19]),
                         pk4f8(fr[20], fr[21], fr[22], fr[23]) };
            u32x4 o1 = { pk4f8(fr[8],  fr[9],  fr[10], fr[11]),
                         pk4f8(fr[12], fr[13], fr[14], fr[15]),
                         pk4f8(fr[24], fr[25], fr[26], fr[27]),
                         pk4f8(fr[28], fr[29], fr[30], fr[31]) };
            *(u32x4*)(xa + fbase + lp * 16)        = o0;
            *(u32x4*)(xa + fbase + (lp + 32) * 16) = o1;
        }
    } else if (bx < 1536) {
        // ---- beta tile: k tk*64..+63, n tn*64..+63 ----
        const int tile = bx - 1024, tk = tile & 31, tn = tile >> 5;
        {   // phase 1: beta[k][n] 64x64 -> LDS [k][68]
            const int r = tid >> 2, c0 = (tid & 3) * 16;
            const float* src = beta + (size_t)(tk * 64 + r) * N + tn * 64 + c0;
            #pragma unroll
            for (int j = 0; j < 4; ++j)
                *(f32x4*)&tls[r * 68 + c0 + j * 4] = *(const f32x4*)(src + j * 4);
        }
        __syncthreads();
        {   // phase 2: frag-major transpose + L1. wave f -> (nt_f=f>>1,ks_f=f&1)
            const int f = tid >> 6, l = tid & 63;
            const int nt_f = f >> 1, ks_f = f & 1;
            const int nl = l & 31, h = l >> 5;
            const int nloc = nt_f * 32 + nl;
            const int kb = ks_f * 32 + h * 8;
            float v0[8], v1[8];
            float s = 0.f;
            #pragma unroll
            for (int j = 0; j < 8; ++j) {
                v0[j] = tls[(kb + j) * 68 + nloc];
                v1[j] = tls[(kb + 16 + j) * 68 + nloc];
                s += fabsf(v0[j]) + fabsf(v1[j]);
            }
            s += __shfl_xor(s, 32);
            if (nl == l)   // h == 0 lanes
                partials[(tk * 2 + ks_f) * 1024 + tn * 64 + nloc] = s;
            u32x4 o = { pk4f8(v0[0], v0[1], v0[2], v0[3]),
                        pk4f8(v0[4], v0[5], v0[6], v0[7]),
                        pk4f8(v1[0], v1[1], v1[2], v1[3]),
                        pk4f8(v1[4], v1[5], v1[6], v1[7]) };
            const size_t fbase =
                ((size_t)(tn * 2 + nt_f) * 64 + (tk * 2 + ks_f)) * 1024;
            *(u32x4*)(bt + fbase + l * 16) = o;
        }
    } else {
        const int b = bx - 1536;
        const int wv = tid >> 6, lane = tid & 63;
        const int row = b * 4 + wv;
        const f32x4* w4 = (const f32x4*)(W2 + (size_t)row * NHID);
        float acc = 0.f;
        #pragma unroll
        for (int i = 0; i < 16; ++i) {
            f32x4 v = w4[i * 64 + lane];
            acc += v[0] + v[1] + v[2] + v[3];
        }
        #pragma unroll
        for (int off = 32; off; off >>= 1) acc += __shfl_down(acc, off);
        if (lane == 0) wsum[row] = acc;
    }
}

// =================== main GEMM: pure-register, L2-fed, barrier-free =========
// 512 blocks x 256 thr (4 waves). Wave -> output tile (a: 64 rows, b: 32 cols).
// XCD c owns a in [8c, 8c+8): per-XCD L2 set = 1MB A + 2MB B.
// Per wave: 64 iters {load A0,A1,B frag (1KB dwordx4 each) + 4 MFMA 32x32x16},
// depth-4 register ring, full unroll, no LDS, no barriers.
__global__ void __launch_bounds__(256, 2) gemm_kernel(
    const char* __restrict__ xa, const char* __restrict__ bt,
    const float* __restrict__ y,
    const float* __restrict__ partials, const float* __restrict__ wsum,
    const float* __restrict__ bias_lin, const float* __restrict__ bias2,
    float* __restrict__ out) {
    const int tid = threadIdx.x, lane = tid & 63, w = tid >> 6;   // w: 0..3
    const int c = blockIdx.x & 7, local = blockIdx.x >> 3;        // c = XCD
    const int a = c * 8 + (local >> 3);          // 0..63 (64-row tile)
    const int b = (local & 7) * 4 + w;           // 0..31 (32-col tile)

    const char* a0p = xa + ((size_t)(2 * a) * 64) * 1024 + lane * 16;
    const char* a1p = a0p + 64 * 1024;
    const char* bp  = bt + ((size_t)b * 64) * 1024 + lane * 16;

    f32x16 acc0 = (f32x16)0.f, acc1 = (f32x16)0.f;

    lx2 A0[4], A1[4], Bf[4];
    #define LDSET(s, ks)                                            \
        A0[s] = *(const lx2*)(a0p + (ks) * 1024);                   \
        A1[s] = *(const lx2*)(a1p + (ks) * 1024);                   \
        Bf[s] = *(const lx2*)(bp  + (ks) * 1024);

    LDSET(0, 0)
    LDSET(1, 1)
    LDSET(2, 2)
    #pragma unroll
    for (int ks = 0; ks < 64; ++ks) {
        const int s = ks & 3;
        if (ks + 3 < 64) { LDSET((ks + 3) & 3, ks + 3) }
        acc0 = __builtin_amdgcn_mfma_f32_32x32x16_fp8_fp8(A0[s].x, Bf[s].x, acc0, 0, 0, 0);
        acc1 = __builtin_amdgcn_mfma_f32_32x32x16_fp8_fp8(A1[s].x, Bf[s].x, acc1, 0, 0, 0);
        acc0 = __builtin_amdgcn_mfma_f32_32x32x16_fp8_fp8(A0[s].y, Bf[s].y, acc0, 0, 0, 0);
        acc1 = __builtin_amdgcn_mfma_f32_32x32x16_fp8_fp8(A1[s].y, Bf[s].y, acc1, 0, 0, 0);
    }
    #undef LDSET

    // ---- epilogue: 32x32 C/D: col=lane&31, row=(reg&3)+8*(reg>>2)+4*(lane>>5)
    const int rl = lane & 31, h = lane >> 5;
    const int gc = b * 32 + rl;
    float bsum = 0.f;
    #pragma unroll 8
    for (int p = 0; p < 64; ++p) bsum += partials[p * 1024 + gc];
    const float be = 0.1f * bsum;
    const float ct = bias_lin[gc] + bias2[gc] + (float)NHID * wsum[gc];
    #pragma unroll
    for (int m = 0; m < 2; ++m) {
        const int rbase = a * 64 + m * 32 + 4 * h;
        #pragma unroll
        for (int g = 0; g < 4; ++g) {
            #pragma unroll
            for (int jr = 0; jr < 4; ++jr) {
                const int row = rbase + g * 8 + jr;
                const size_t idx = (size_t)row * N + gc;
                const float av = (m == 0) ? acc0[g * 4 + jr] : acc1[g * 4 + jr];
                out[idx] = av + ct - be * y[idx];
            }
        }
    }
}

extern "C" void kernel_launch(void* const* d_in, const int* in_sizes, int n_in,
                              void* d_out, int out_size, void* d_ws, size_t ws_size,
                              hipStream_t stream) {
    const float* x        = (const float*)d_in[0];
    const float* y        = (const float*)d_in[1];
    const float* beta     = (const float*)d_in[2];
    const float* bias_lin = (const float*)d_in[3];
    const float* W2       = (const float*)d_in[5];
    const float* bias2    = (const float*)d_in[7];
    float* out = (float*)d_out;

    float* partials = (float*)d_ws;                        // [64][1024]
    float* wsum     = partials + 64 * 1024;                // [1024]
    char*  xa       = (char*)(wsum + 1024);                // [M/32][K/32] frags
    char*  bts      = xa + (size_t)M * K;                  // [N/32][K/32] frags

    pre_kernel<<<1792, 256, 0, stream>>>(x, beta, W2, xa, bts, partials, wsum);
    gemm_kernel<<<512, 256, 0, stream>>>(xa, bts, y, partials, wsum,
                                         bias_lin, bias2, out);
}

// Round 16
// 40.644 us; speedup vs baseline: 1.1545x; 1.1545x over previous
//
#include <hip/hip_runtime.h>
#include <hip/hip_bf16.h>

// out[i][j] = (x@beta)[i][j] - 0.1*y[i][j]*||beta[:,j]||_1
//             + (4096*rowsum(W2)[j] + bias2[j] + bias_lin[j])
// M=4096, K=2048, N=1024. adv==1 always.
//
// Round 16: r12 fp8 front + 8-phase-style schedule (T3+T4+T5 port).
// Gemm: BM=128 BN=128, 8 waves (2m x 4n, wave tile 64x32), grid 256 =
// 1 block/CU, 3 LDS bufs (96KB). Per K-tile (128 fp8 k's) = 2 phases:
//   {6 ds_read_b128 ; issue 2 gll16(t+2) ; s_barrier ; lgkmcnt(0)+schedbar ;
//    setprio(1) 16 MFMA setprio(0) ; s_barrier}
// vmcnt(4) ONCE per K-tile (before the tile-closing barrier) -- stage(t+2)
// stays in flight across barriers; never drained mid-loop.

typedef float    f32x4  __attribute__((ext_vector_type(4)));
typedef unsigned u32x4  __attribute__((ext_vector_type(4)));
typedef long     lx2    __attribute__((ext_vector_type(2)));

constexpr int M = 4096;
constexpr int N = 1024;
constexpr int K = 2048;
constexpr int NHID = 4096;

__device__ __forceinline__ unsigned pk4f8(float a, float b, float c, float d) {
    unsigned v = __builtin_amdgcn_cvt_pk_fp8_f32(a, b, 0, false);
    v = __builtin_amdgcn_cvt_pk_fp8_f32(c, d, v, true);
    return v;
}

__device__ __forceinline__ void gll16(const void* g, void* l) {
    __builtin_amdgcn_global_load_lds(
        (const __attribute__((address_space(1))) void*)g,
        (__attribute__((address_space(3))) void*)l, 16, 0, 0);
}

// =================== pre (identical to round 12; verified absmax 64) ========
__global__ void __launch_bounds__(256) pre_kernel(
    const float* __restrict__ x, const float* __restrict__ beta,
    const float* __restrict__ W2,
    char* __restrict__ xb, char* __restrict__ bt,
    float* __restrict__ partials,   // [32][1024]
    float* __restrict__ wsum) {     // [1024]
    __shared__ float tls[64 * 132];
    const int bx = blockIdx.x, tid = threadIdx.x;
    if (bx < 1024) {
        const int rt = bx >> 4, kt = bx & 15;
        {
            const int r = tid >> 2, c0 = (tid & 3) * 32;
            const float* src = x + (size_t)(rt * 64 + r) * K + kt * 128 + c0;
            #pragma unroll
            for (int i = 0; i < 8; ++i)
                *(f32x4*)&tls[r * 132 + c0 + i * 4] = *(const f32x4*)(src + i * 4);
        }
        __syncthreads();
        {
            const int r = tid >> 2;
            const float* row = &tls[r * 132];
            char* orow = xb + (size_t)(rt * 64 + r) * K + kt * 128;
            #pragma unroll
            for (int uu = 0; uu < 2; ++uu) {
                const int u = (tid & 3) + uu * 4;
                const int p = u >> 2, q = u & 3;
                const float* h0 = row + p * 64 + q * 8;
                const float* h1 = h0 + 32;
                u32x4 o = { pk4f8(h0[0], h0[1], h0[2], h0[3]),
                            pk4f8(h0[4], h0[5], h0[6], h0[7]),
                            pk4f8(h1[0], h1[1], h1[2], h1[3]),
                            pk4f8(h1[4], h1[5], h1[6], h1[7]) };
                *(u32x4*)(orow + u * 16) = o;
            }
        }
    } else if (bx < 1536) {
        const int tile = bx - 1024, tk = tile & 31, tn = tile >> 5;
        {
            const int r = tid >> 2, c0 = (tid & 3) * 16;
            const float* src = beta + (size_t)(tk * 64 + r) * N + tn * 64 + c0;
            #pragma unroll
            for (int j = 0; j < 4; ++j)
                *(f32x4*)&tls[r * 68 + c0 + j * 4] = *(const f32x4*)(src + j * 4);
        }
        __syncthreads();
        {
            const int n = tid >> 2, q = tid & 3;
            float s = 0.f;
            float v0[8], v1[8];
            #pragma unroll
            for (int j = 0; j < 8; ++j) {
                v0[j] = tls[(q * 8 + j) * 68 + n];
                v1[j] = tls[(32 + q * 8 + j) * 68 + n];
                s += fabsf(v0[j]) + fabsf(v1[j]);
            }
            s += __shfl_xor(s, 1);
            s += __shfl_xor(s, 2);
            if (q == 0) partials[tk * 1024 + tn * 64 + n] = s;
            u32x4 o = { pk4f8(v0[0], v0[1], v0[2], v0[3]),
                        pk4f8(v0[4], v0[5], v0[6], v0[7]),
                        pk4f8(v1[0], v1[1], v1[2], v1[3]),
                        pk4f8(v1[4], v1[5], v1[6], v1[7]) };
            *(u32x4*)(bt + (size_t)(tn * 64 + n) * K + tk * 64 + q * 16) = o;
        }
    } else {
        const int b = bx - 1536;
        const int wv = tid >> 6, lane = tid & 63;
        const int row = b * 4 + wv;
        const f32x4* w4 = (const f32x4*)(W2 + (size_t)row * NHID);
        float acc = 0.f;
        #pragma unroll
        for (int i = 0; i < 16; ++i) {
            f32x4 v = w4[i * 64 + lane];
            acc += v[0] + v[1] + v[2] + v[3];
        }
        #pragma unroll
        for (int off = 32; off; off >>= 1) acc += __shfl_down(acc, off);
        if (lane == 0) wsum[row] = acc;
    }
}

// =================== main GEMM: fp8, 2-phase-per-K-tile 8ph-style ===========
constexpr int BKu = 128;             // fp8 bytes per K-tile (K=128)
constexpr int NT  = K / BKu;         // 16
constexpr int TSZ = 128 * BKu;       // 16KB per operand tile

__global__ void __launch_bounds__(512, 2) gemm_kernel(
    const char* __restrict__ xb, const char* __restrict__ bt,
    const float* __restrict__ y,
    const float* __restrict__ partials, const float* __restrict__ wsum,
    const float* __restrict__ bias_lin, const float* __restrict__ bias2,
    float* __restrict__ out) {
    __shared__ __align__(16) char Al[3 * TSZ];   // 48KB
    __shared__ __align__(16) char Bl[3 * TSZ];   // 48KB

    const int tid = threadIdx.x, lane = tid & 63, w = tid >> 6;   // w: 0..7
    const int wm = w >> 2, wn = w & 3;                            // 2m x 4n
    // XCD swizzle: xcd c gets mb in [4c,4c+4), all 8 nb (grid 256 = 8 x 32)
    const int c = blockIdx.x & 7, local = blockIdx.x >> 3;
    const int mb = (c << 2) + (local >> 3);
    const int nb = local & 7;
    const int brow = mb * 128, bcol = nb * 128;

    // ---- staging: per-lane source swizzle, linear LDS dest (tid*16 + i*8K)
    const int schk = (tid & 7) ^ ((tid >> 3) & 7);
    const char* asrc = xb + (size_t)(brow + (tid >> 3)) * K + schk * 16;
    const char* bsrc = bt + (size_t)(bcol + (tid >> 3)) * K + schk * 16;

    auto STAGE_A = [&](int buf, int t) {
        gll16(asrc + (size_t)t * BKu, &Al[buf * TSZ + tid * 16]);
        gll16(asrc + (size_t)64 * K + (size_t)t * BKu,
              &Al[buf * TSZ + 8192 + tid * 16]);
    };
    auto STAGE_B = [&](int buf, int t) {
        gll16(bsrc + (size_t)t * BKu, &Bl[buf * TSZ + tid * 16]);
        gll16(bsrc + (size_t)64 * K + (size_t)t * BKu,
              &Bl[buf * TSZ + 8192 + tid * 16]);
    };

    // ---- fragment read offsets: unit (p*4+q) ^ (row&7), rows 128B ----
    const int r = lane & 15, q = lane >> 4;
    int aoff[4][2], boff[2][2];
    #pragma unroll
    for (int m = 0; m < 4; ++m)
        #pragma unroll
        for (int p = 0; p < 2; ++p) {
            const int row = wm * 64 + m * 16 + r;
            aoff[m][p] = row * 128 + (((p * 4 + q) ^ (r & 7)) * 16);
        }
    #pragma unroll
    for (int n = 0; n < 2; ++n)
        #pragma unroll
        for (int p = 0; p < 2; ++p) {
            const int row = wn * 32 + n * 16 + r;
            boff[n][p] = row * 128 + (((p * 4 + q) ^ (r & 7)) * 16);
        }

    f32x4 acc[4][2];
    #pragma unroll
    for (int m = 0; m < 4; ++m)
        #pragma unroll
        for (int n = 0; n < 2; ++n) acc[m][n] = (f32x4)0.f;

    // ---- prologue: fill pipeline 2 deep ----
    STAGE_A(0, 0); STAGE_B(0, 0);
    STAGE_A(1, 1); STAGE_B(1, 1);
    asm volatile("s_waitcnt vmcnt(4)" ::: "memory");   // tile 0 landed
    __builtin_amdgcn_s_barrier();

    int b0 = 0, b1 = 1, b2 = 2;
    for (int t = 0; t < NT; ++t) {
        const char* A = &Al[b0 * TSZ];
        const char* B = &Bl[b0 * TSZ];

        // ======== phase 0 (k-slices 0,1) ========
        lx2 pa[4], pb[2];
        #pragma unroll
        for (int m = 0; m < 4; ++m) pa[m] = *(const lx2*)&A[aoff[m][0]];
        #pragma unroll
        for (int n = 0; n < 2; ++n) pb[n] = *(const lx2*)&B[boff[n][0]];
        if (t + 2 < NT) STAGE_A(b2, t + 2);
        __builtin_amdgcn_s_barrier();
        asm volatile("s_waitcnt lgkmcnt(0)" ::: "memory");
        __builtin_amdgcn_sched_barrier(0);
        __builtin_amdgcn_s_setprio(1);
        #pragma unroll
        for (int m = 0; m < 4; ++m)
            #pragma unroll
            for (int n = 0; n < 2; ++n)
                acc[m][n] = __builtin_amdgcn_mfma_f32_16x16x32_fp8_fp8(
                    pa[m].x, pb[n].x, acc[m][n], 0, 0, 0);
        #pragma unroll
        for (int m = 0; m < 4; ++m)
            #pragma unroll
            for (int n = 0; n < 2; ++n)
                acc[m][n] = __builtin_amdgcn_mfma_f32_16x16x32_fp8_fp8(
                    pa[m].y, pb[n].y, acc[m][n], 0, 0, 0);
        __builtin_amdgcn_s_setprio(0);
        __builtin_amdgcn_s_barrier();

        // ======== phase 1 (k-slices 2,3) ========
        #pragma unroll
        for (int m = 0; m < 4; ++m) pa[m] = *(const lx2*)&A[aoff[m][1]];
        #pragma unroll
        for (int n = 0; n < 2; ++n) pb[n] = *(const lx2*)&B[boff[n][1]];
        if (t + 2 < NT) STAGE_B(b2, t + 2);
        __builtin_amdgcn_s_barrier();
        asm volatile("s_waitcnt lgkmcnt(0)" ::: "memory");
        __builtin_amdgcn_sched_barrier(0);
        __builtin_amdgcn_s_setprio(1);
        #pragma unroll
        for (int m = 0; m < 4; ++m)
            #pragma unroll
            for (int n = 0; n < 2; ++n)
                acc[m][n] = __builtin_amdgcn_mfma_f32_16x16x32_fp8_fp8(
                    pa[m].x, pb[n].x, acc[m][n], 0, 0, 0);
        #pragma unroll
        for (int m = 0; m < 4; ++m)
            #pragma unroll
            for (int n = 0; n < 2; ++n)
                acc[m][n] = __builtin_amdgcn_mfma_f32_16x16x32_fp8_fp8(
                    pa[m].y, pb[n].y, acc[m][n], 0, 0, 0);
        __builtin_amdgcn_s_setprio(0);
        // tile-closing: publish stage(t+1) completion; keep stage(t+2) in flight
        if (t < NT - 1) {
            if (t + 2 < NT) { asm volatile("s_waitcnt vmcnt(4)" ::: "memory"); }
            else            { asm volatile("s_waitcnt vmcnt(0)" ::: "memory"); }
        }
        __builtin_amdgcn_s_barrier();

        const int tmp = b0; b0 = b1; b1 = b2; b2 = tmp;
    }

    // ---- epilogue: out = acc + cterm[col] - 0.1*bnorm[col]*y ----
    #pragma unroll
    for (int n = 0; n < 2; ++n) {
        const int gc = bcol + wn * 32 + n * 16 + r;
        float bsum = 0.f;
        #pragma unroll 8
        for (int tk = 0; tk < 32; ++tk) bsum += partials[tk * 1024 + gc];
        const float be = 0.1f * bsum;
        const float ct = bias_lin[gc] + bias2[gc] + (float)NHID * wsum[gc];
        #pragma unroll
        for (int m = 0; m < 4; ++m) {
            const int gr0 = brow + wm * 64 + m * 16 + q * 4;
            f32x4 v = acc[m][n];
            #pragma unroll
            for (int rr = 0; rr < 4; ++rr) {
                size_t idx = (size_t)(gr0 + rr) * N + gc;
                out[idx] = v[rr] + ct - be * y[idx];
            }
        }
    }
}

extern "C" void kernel_launch(void* const* d_in, const int* in_sizes, int n_in,
                              void* d_out, int out_size, void* d_ws, size_t ws_size,
                              hipStream_t stream) {
    const float* x        = (const float*)d_in[0];
    const float* y        = (const float*)d_in[1];
    const float* beta     = (const float*)d_in[2];
    const float* bias_lin = (const float*)d_in[3];
    const float* W2       = (const float*)d_in[5];
    const float* bias2    = (const float*)d_in[7];
    float* out = (float*)d_out;

    float* partials = (float*)d_ws;                        // [32][1024]
    float* wsum     = partials + 32 * 1024;                // [1024]
    char*  xb       = (char*)(wsum + 1024);                // [M][K] fp8 permuted
    char*  bts      = xb + (size_t)M * K;                  // [N][K] fp8 permuted

    pre_kernel<<<1792, 256, 0, stream>>>(x, beta, W2, xb, bts, partials, wsum);
    gemm_kernel<<<256, 512, 0, stream>>>(xb, bts, y, partials, wsum,
                                         bias_lin, bias2, out);
}

// Round 17
// 34.761 us; speedup vs baseline: 1.3499x; 1.1692x over previous
//
#include <hip/hip_runtime.h>
#include <hip/hip_bf16.h>

// out[i][j] = (x@beta)[i][j] - 0.1*y[i][j]*||beta[:,j]||_1
//             + (4096*rowsum(W2)[j] + bias2[j] + bias_lin[j])
// M=4096, K=2048, N=1024. adv==1 always.
//
// Round 17: r12 (best, 36.1us) + vectorized epilogue.
// K-loop/pre byte-identical to r12. Epilogue: acc -> LDS (stride-66 rows,
// <=2-way conflicts = free), be/ct computed once by 64 threads into LDS,
// then 4x f32x4 y-loads + 4x f32x4 out-stores per thread (256B/row/wave).

typedef float    f32x4  __attribute__((ext_vector_type(4)));
typedef unsigned u32x4  __attribute__((ext_vector_type(4)));
typedef long     lx2    __attribute__((ext_vector_type(2)));

constexpr int M = 4096;
constexpr int N = 1024;
constexpr int K = 2048;
constexpr int NHID = 4096;

__device__ __forceinline__ unsigned pk4f8(float a, float b, float c, float d) {
    unsigned v = __builtin_amdgcn_cvt_pk_fp8_f32(a, b, 0, false);
    v = __builtin_amdgcn_cvt_pk_fp8_f32(c, d, v, true);
    return v;
}

__device__ __forceinline__ void gll16(const void* g, void* l) {
    __builtin_amdgcn_global_load_lds(
        (const __attribute__((address_space(1))) void*)g,
        (__attribute__((address_space(3))) void*)l, 16, 0, 0);
}

// =================== pre (identical to round 12) ============================
__global__ void __launch_bounds__(256) pre_kernel(
    const float* __restrict__ x, const float* __restrict__ beta,
    const float* __restrict__ W2,
    char* __restrict__ xb, char* __restrict__ bt,
    float* __restrict__ partials,   // [32][1024]
    float* __restrict__ wsum) {     // [1024]
    __shared__ float tls[64 * 132];
    const int bx = blockIdx.x, tid = threadIdx.x;
    if (bx < 1024) {
        const int rt = bx >> 4, kt = bx & 15;
        {
            const int r = tid >> 2, c0 = (tid & 3) * 32;
            const float* src = x + (size_t)(rt * 64 + r) * K + kt * 128 + c0;
            #pragma unroll
            for (int i = 0; i < 8; ++i)
                *(f32x4*)&tls[r * 132 + c0 + i * 4] = *(const f32x4*)(src + i * 4);
        }
        __syncthreads();
        {
            const int r = tid >> 2;
            const float* row = &tls[r * 132];
            char* orow = xb + (size_t)(rt * 64 + r) * K + kt * 128;
            #pragma unroll
            for (int uu = 0; uu < 2; ++uu) {
                const int u = (tid & 3) + uu * 4;
                const int p = u >> 2, q = u & 3;
                const float* h0 = row + p * 64 + q * 8;
                const float* h1 = h0 + 32;
                u32x4 o = { pk4f8(h0[0], h0[1], h0[2], h0[3]),
                            pk4f8(h0[4], h0[5], h0[6], h0[7]),
                            pk4f8(h1[0], h1[1], h1[2], h1[3]),
                            pk4f8(h1[4], h1[5], h1[6], h1[7]) };
                *(u32x4*)(orow + u * 16) = o;
            }
        }
    } else if (bx < 1536) {
        const int tile = bx - 1024, tk = tile & 31, tn = tile >> 5;
        {
            const int r = tid >> 2, c0 = (tid & 3) * 16;
            const float* src = beta + (size_t)(tk * 64 + r) * N + tn * 64 + c0;
            #pragma unroll
            for (int j = 0; j < 4; ++j)
                *(f32x4*)&tls[r * 68 + c0 + j * 4] = *(const f32x4*)(src + j * 4);
        }
        __syncthreads();
        {
            const int n = tid >> 2, q = tid & 3;
            float s = 0.f;
            float v0[8], v1[8];
            #pragma unroll
            for (int j = 0; j < 8; ++j) {
                v0[j] = tls[(q * 8 + j) * 68 + n];
                v1[j] = tls[(32 + q * 8 + j) * 68 + n];
                s += fabsf(v0[j]) + fabsf(v1[j]);
            }
            s += __shfl_xor(s, 1);
            s += __shfl_xor(s, 2);
            if (q == 0) partials[tk * 1024 + tn * 64 + n] = s;
            u32x4 o = { pk4f8(v0[0], v0[1], v0[2], v0[3]),
                        pk4f8(v0[4], v0[5], v0[6], v0[7]),
                        pk4f8(v1[0], v1[1], v1[2], v1[3]),
                        pk4f8(v1[4], v1[5], v1[6], v1[7]) };
            *(u32x4*)(bt + (size_t)(tn * 64 + n) * K + tk * 64 + q * 16) = o;
        }
    } else {
        const int b = bx - 1536;
        const int wv = tid >> 6, lane = tid & 63;
        const int row = b * 4 + wv;
        const f32x4* w4 = (const f32x4*)(W2 + (size_t)row * NHID);
        float acc = 0.f;
        #pragma unroll
        for (int i = 0; i < 16; ++i) {
            f32x4 v = w4[i * 64 + lane];
            acc += v[0] + v[1] + v[2] + v[3];
        }
        #pragma unroll
        for (int off = 32; off; off >>= 1) acc += __shfl_down(acc, off);
        if (lane == 0) wsum[row] = acc;
    }
}

// =================== main GEMM (r12 K-loop + vectorized epilogue) ===========
constexpr int BKu = 128;
constexpr int NT  = K / BKu;         // 16
constexpr int ASZ = 128 * BKu;       // 16384 B
constexpr int BSZ = 64 * BKu;        // 8192 B

__global__ void __launch_bounds__(512, 4) gemm_kernel(
    const char* __restrict__ xb, const char* __restrict__ bt,
    const float* __restrict__ y,
    const float* __restrict__ partials, const float* __restrict__ wsum,
    const float* __restrict__ bias_lin, const float* __restrict__ bias2,
    float* __restrict__ out) {
    __shared__ __align__(16) char Al[3 * ASZ];   // 48KB (epilogue scratch T)
    __shared__ __align__(16) char Bl[3 * BSZ];   // 24KB (epilogue bev/ctv)

    const int tid = threadIdx.x, lane = tid & 63, w = tid >> 6;   // w: 0..7
    const int wm = w >> 1, wn = w & 1;                            // 4m x 2n
    const int c = blockIdx.x & 7, local = blockIdx.x >> 3;
    const int mb = ((c & 1) << 4) + (local >> 2);
    const int nb = ((c >> 1) << 2) + (local & 3);
    const int brow = mb * 128, bcol = nb * 64;

    // ---- staging (per-lane source swizzle, linear LDS dest) ----
    const int srow = lane >> 3;
    const int sulog = (lane & 7) ^ srow;
    const char* asrc0 = xb + (size_t)(brow + w * 16 + srow) * K + sulog * 16;
    const char* asrc1 = asrc0 + (size_t)8 * K;
    const char* bsrc  = bt + (size_t)(bcol + w * 8 + srow) * K + sulog * 16;

    auto STAGE = [&](int buf, int t) {
        gll16(asrc0 + t * BKu, &Al[buf * ASZ + w * 2048]);
        gll16(asrc1 + t * BKu, &Al[buf * ASZ + w * 2048 + 1024]);
        gll16(bsrc  + t * BKu, &Bl[buf * BSZ + w * 1024]);
    };

    // ---- fragment read offsets ----
    const int r = lane & 15, q = lane >> 4;
    int aoff[2][2], boff[2][2];
    #pragma unroll
    for (int m = 0; m < 2; ++m)
        #pragma unroll
        for (int p = 0; p < 2; ++p) {
            const int row = wm * 32 + m * 16 + r;
            aoff[m][p] = row * 128 + (((p * 4 + q) ^ (r & 7)) * 16);
        }
    #pragma unroll
    for (int n = 0; n < 2; ++n)
        #pragma unroll
        for (int p = 0; p < 2; ++p) {
            const int row = wn * 32 + n * 16 + r;
            boff[n][p] = row * 128 + (((p * 4 + q) ^ (r & 7)) * 16);
        }

    f32x4 acc[2][2];
    #pragma unroll
    for (int m = 0; m < 2; ++m)
        #pragma unroll
        for (int n = 0; n < 2; ++n) acc[m][n] = (f32x4)0.f;

    auto COMPUTE = [&](int buf) {
        const char* A = &Al[buf * ASZ];
        const char* B = &Bl[buf * BSZ];
        #pragma unroll
        for (int p = 0; p < 2; ++p) {
            lx2 a0 = *(const lx2*)&A[aoff[0][p]];
            lx2 a1 = *(const lx2*)&A[aoff[1][p]];
            lx2 b0 = *(const lx2*)&B[boff[0][p]];
            lx2 b1 = *(const lx2*)&B[boff[1][p]];
            acc[0][0] = __builtin_amdgcn_mfma_f32_16x16x32_fp8_fp8(a0.x, b0.x, acc[0][0], 0, 0, 0);
            acc[0][1] = __builtin_amdgcn_mfma_f32_16x16x32_fp8_fp8(a0.x, b1.x, acc[0][1], 0, 0, 0);
            acc[1][0] = __builtin_amdgcn_mfma_f32_16x16x32_fp8_fp8(a1.x, b0.x, acc[1][0], 0, 0, 0);
            acc[1][1] = __builtin_amdgcn_mfma_f32_16x16x32_fp8_fp8(a1.x, b1.x, acc[1][1], 0, 0, 0);
            acc[0][0] = __builtin_amdgcn_mfma_f32_16x16x32_fp8_fp8(a0.y, b0.y, acc[0][0], 0, 0, 0);
            acc[0][1] = __builtin_amdgcn_mfma_f32_16x16x32_fp8_fp8(a0.y, b1.y, acc[0][1], 0, 0, 0);
            acc[1][0] = __builtin_amdgcn_mfma_f32_16x16x32_fp8_fp8(a1.y, b0.y, acc[1][0], 0, 0, 0);
            acc[1][1] = __builtin_amdgcn_mfma_f32_16x16x32_fp8_fp8(a1.y, b1.y, acc[1][1], 0, 0, 0);
        }
    };

    STAGE(0, 0);
    STAGE(1, 1);
    for (int t = 0; t < NT; ++t) {
        if (t < NT - 1) { asm volatile("s_waitcnt vmcnt(3)" ::: "memory"); }
        else            { asm volatile("s_waitcnt vmcnt(0)" ::: "memory"); }
        __builtin_amdgcn_s_barrier();
        __builtin_amdgcn_sched_barrier(0);
        if (t + 2 < NT) STAGE((t + 2) % 3, t + 2);
        COMPUTE(t % 3);
    }

    // ---- vectorized epilogue ----
    __syncthreads();                       // staging LDS now free
    float* T   = (float*)Al;               // [128][66] floats = 33792B < 48KB
    float* bev = (float*)Bl;               // [64]
    float* ctv = bev + 64;                 // [64]

    // scatter acc -> T (rows stride 66: 4-row offsets 0,8,16,24 -> <=2-way)
    #pragma unroll
    for (int m = 0; m < 2; ++m)
        #pragma unroll
        for (int n = 0; n < 2; ++n) {
            const int lr = wm * 32 + m * 16 + q * 4;
            const int lc = wn * 32 + n * 16 + r;
            #pragma unroll
            for (int rr = 0; rr < 4; ++rr)
                T[(lr + rr) * 66 + lc] = acc[m][n][rr];
        }
    // 64 threads compute per-column be/ct once
    if (tid < 64) {
        const int gc = bcol + tid;
        float bsum = 0.f;
        #pragma unroll 8
        for (int tk = 0; tk < 32; ++tk) bsum += partials[tk * 1024 + gc];
        bev[tid] = 0.1f * bsum;
        ctv[tid] = bias_lin[gc] + bias2[gc] + (float)NHID * wsum[gc];
    }
    __syncthreads();

    // gather + fused y term, f32x4 loads/stores (256B per row per wave)
    const int c4 = tid & 15, r0 = tid >> 4;      // rows r0, r0+32, r0+64, r0+96
    const f32x4 ct4 = *(const f32x4*)&ctv[c4 * 4];
    const f32x4 be4 = *(const f32x4*)&bev[c4 * 4];
    #pragma unroll
    for (int i = 0; i < 4; ++i) {
        const int row = r0 + i * 32;
        f32x4 v = *(const f32x4*)&T[row * 66 + c4 * 4];
        const size_t idx = (size_t)(brow + row) * N + bcol + c4 * 4;
        const f32x4 yv = *(const f32x4*)&y[idx];
        f32x4 o;
        #pragma unroll
        for (int e = 0; e < 4; ++e) o[e] = v[e] + ct4[e] - be4[e] * yv[e];
        *(f32x4*)&out[idx] = o;
    }
}

extern "C" void kernel_launch(void* const* d_in, const int* in_sizes, int n_in,
                              void* d_out, int out_size, void* d_ws, size_t ws_size,
                              hipStream_t stream) {
    const float* x        = (const float*)d_in[0];
    const float* y        = (const float*)d_in[1];
    const float* beta     = (const float*)d_in[2];
    const float* bias_lin = (const float*)d_in[3];
    const float* W2       = (const float*)d_in[5];
    const float* bias2    = (const float*)d_in[7];
    float* out = (float*)d_out;

    float* partials = (float*)d_ws;                        // [32][1024]
    float* wsum     = partials + 32 * 1024;                // [1024]
    char*  xb       = (char*)(wsum + 1024);                // [M][K] fp8 permuted
    char*  bts      = xb + (size_t)M * K;                  // [N][K] fp8 permuted

    pre_kernel<<<1792, 256, 0, stream>>>(x, beta, W2, xb, bts, partials, wsum);
    gemm_kernel<<<512, 512, 0, stream>>>(xb, bts, y, partials, wsum,
                                         bias_lin, bias2, out);
}